// Round 5
// baseline (396.019 us; speedup 1.0000x reference)
//
#include <hip/hip_runtime.h>
#include <hip/hip_fp16.h>

#define NN 20000      // nodes
#define NE 320000     // edges
#define SS 2          // feature axis
#define FIN 128
#define FH 246
#define MPAD 40064    // M (=NN*SS) padded to 64

typedef _Float16 f16x8 __attribute__((ext_vector_type(8)));
typedef float f32x4 __attribute__((ext_vector_type(4)));

// ---------------- degree histogram ----------------
__global__ void degree_kernel(const int* __restrict__ src, const int* __restrict__ dst,
                              int* __restrict__ deg_out, int* __restrict__ deg_in) {
    int e = blockIdx.x * blockDim.x + threadIdx.x;
    if (e < NE) {
        atomicAdd(&deg_out[src[e]], 1);
        atomicAdd(&deg_in[dst[e]], 1);
    }
}

// ---------------- norms + parallel CSR range allocation (fused) ----------------
// ranges PADDED to multiples of 4 (pad slots get src=NN -> zero row) so the
// aggregate can do one aligned ushort4 index load per 4 edges, no tail loop.
__global__ void alloc_kernel(const int* __restrict__ deg_out, const int* __restrict__ deg_in,
                             float* __restrict__ norm_out, float* __restrict__ norm_in,
                             int* __restrict__ row_start, int* __restrict__ cursor,
                             int* __restrict__ counter) {
    __shared__ int smem[256];
    __shared__ int base_s;
    int tid = threadIdx.x;
    int i = blockIdx.x * 256 + tid;
    int v  = (i < NN) ? deg_in[i] : 0;
    int vp = (v + 3) & ~3;                 // padded degree
    smem[tid] = vp;
    __syncthreads();
    for (int off = 1; off < 256; off <<= 1) {
        int t = (tid >= off) ? smem[tid - off] : 0;
        __syncthreads();
        smem[tid] += t;
        __syncthreads();
    }
    int incl = smem[tid];
    if (tid == 0) base_s = atomicAdd(counter, smem[255]);
    __syncthreads();
    if (i < NN) {
        int excl = base_s + incl - vp;     // multiple of 4 by construction
        row_start[i] = excl;
        cursor[i]    = excl;
        norm_out[i] = rsqrtf(fmaxf((float)deg_out[i], 1.0f));
        norm_in[i]  = rsqrtf(fmaxf((float)v, 1.0f));
    }
}

// ---------------- scatter edges into CSR (ushort indices: NN < 65536) ----------
__global__ void scatter_kernel(const int* __restrict__ src, const int* __restrict__ dst,
                               int* __restrict__ cursor, ushort* __restrict__ sorted_src) {
    int e = blockIdx.x * blockDim.x + threadIdx.x;
    if (e < NE) {
        int d = dst[e];
        int pos = atomicAdd(&cursor[d], 1);
        sorted_src[pos] = (ushort)src[e];
    }
}

// ---------------- fill pad slots with src=NN (the zero/dead row) ----------------
__global__ void pad_fill(const int* __restrict__ row_start, const int* __restrict__ deg_in,
                         ushort* __restrict__ sorted_src) {
    int n = blockIdx.x * 256 + threadIdx.x;
    if (n < NN) {
        int d = deg_in[n];
        int beg = row_start[n] + d;
        int end = row_start[n] + ((d + 3) & ~3);
        for (int p = beg; p < end; ++p) sorted_src[p] = (ushort)NN;
    }
}

// ---------------- W pre-split (all 3 layers in one launch) ----------------
__global__ void convert_w_all(const float* __restrict__ W0, const float* __restrict__ W1,
                              const float* __restrict__ W2,
                              ushort* __restrict__ Wh0, ushort* __restrict__ Wl0,
                              ushort* __restrict__ Wh1, ushort* __restrict__ Wl1,
                              ushort* __restrict__ Wh2, ushort* __restrict__ Wl2) {
    int n = blockIdx.x, k = threadIdx.x;
    const float* W; ushort* Wh; ushort* Wl; int K;
    if (blockIdx.y == 0)      { W = W0; Wh = Wh0; Wl = Wl0; K = FIN; }
    else if (blockIdx.y == 1) { W = W1; Wh = Wh1; Wl = Wl1; K = FH; }
    else                      { W = W2; Wh = Wh2; Wl = Wl2; K = FH; }
    float v = (k < K && n < 246) ? W[k * 246 + n] : 0.f;
    _Float16 h = (_Float16)v;
    _Float16 l = (_Float16)(v - (float)h);
    Wh[n * 256 + k] = *(ushort*)&h;
    Wl[n * 256 + k] = *(ushort*)&l;
}

__global__ void init_out(float* __restrict__ out, const float* __restrict__ fcb,
                         float* __restrict__ norm_out) {
    int i = blockIdx.x * 256 + threadIdx.x;
    if (i < NN) out[i] = fcb[0];
    if (i == 0) norm_out[NN] = 0.f;   // dead-norm entry for layer-0 pad edges
}

// ---------------- zero the M-pad rows of the K-tiled A buffers ----------------
// A_tiled layout: half at (kt*MPAD + m)*32 + kk, kt<8, pads m in [40000,40064).
// (KP=128 layout's kt<4 pads are the same flat positions.)
__global__ void zero_pads(ushort* __restrict__ Ah, ushort* __restrict__ Al) {
    int i = blockIdx.x * 256 + threadIdx.x;        // 4096 uint2 per buffer
    if (i < 4096) {
        int kt = i >> 9, r = i & 511;
        int m = NN * SS + (r >> 3), j = r & 7;
        size_t o = ((size_t)kt * MPAD + m) * 8 + j;
        ((unsigned long long*)Ah)[o] = 0ull;
        ((unsigned long long*)Al)[o] = 0ull;
    }
}

// ---------------- XCD-pinned chunk-tiled gather-aggregate, split-f16 output ----------
// r22: output layout is now K-TILED PANEL [K/32][MPAD][32] halfs so the GEMM
// can read A fragments directly from global fully coalesced (1 KB/wave-load).
// Store: m = n*2 + (idx>=IHALF), ik = idx&(IHALF-1): kt=ik>>3, kk4=ik&7.
// Keeps r21's index prefetch + nontemporal stores; r18-proven geometry
// (16 lanes/node, 256B chunks, 4 nodes/wave). Pure segment-sum (norms folded
// into producer); ushort4 packed indices, ranges 4-padded (pad src=NN -> zero
// row). NORM=true only for layer 0 (feat can't be prescaled in-place).
template<int F4ROW, int NCH, bool NORM>
__global__ void aggregate4(const float* __restrict__ h,
                           const int* __restrict__ row_start,
                           const int* __restrict__ deg_in,
                           const ushort* __restrict__ sorted_src,
                           const float* __restrict__ norm_out,
                           const float* __restrict__ norm_in,
                           ushort* __restrict__ Ah, ushort* __restrict__ Al) {
    constexpr int IHALF = F4ROW / 2;
    int g  = threadIdx.x >> 4;              // 0..7: node sub-index
    int l  = threadIdx.x & 15;              // float4 within chunk
    int cb = blockIdx.x & (NCH - 1);        // chunk (XCD-pinned axis)
    int nb = blockIdx.x / NCH;              // node group
    int n  = nb * 8 + g;
    if (n >= NN) return;
    int idx = cb * 16 + l;                  // < F4ROW (= NCH*16)
    const float4* hv = (const float4*)h;
    int beg = row_start[n];
    int end = beg + ((deg_in[n] + 3) & ~3);
    float4 acc = {0.f, 0.f, 0.f, 0.f};
    ushort4 ss;
    if (beg < end) ss = *(const ushort4*)&sorted_src[beg];   // 8B aligned (beg%4==0)
    for (int i = beg; i < end; i += 4) {
        ushort4 cur = ss;
        if (i + 4 < end) ss = *(const ushort4*)&sorted_src[i + 4];   // prefetch
        int s0 = cur.x, s1 = cur.y, s2 = cur.z, s3 = cur.w;
        if (NORM) {
            float n0 = norm_out[s0], n1 = norm_out[s1];
            float n2 = norm_out[s2], n3 = norm_out[s3];
            float4 v0 = hv[(size_t)(s0 < NN ? s0 : NN - 1) * F4ROW + idx];
            float4 v1 = hv[(size_t)(s1 < NN ? s1 : NN - 1) * F4ROW + idx];
            float4 v2 = hv[(size_t)(s2 < NN ? s2 : NN - 1) * F4ROW + idx];
            float4 v3 = hv[(size_t)(s3 < NN ? s3 : NN - 1) * F4ROW + idx];
            acc.x += v0.x * n0 + v1.x * n1 + v2.x * n2 + v3.x * n3;
            acc.y += v0.y * n0 + v1.y * n1 + v2.y * n2 + v3.y * n3;
            acc.z += v0.z * n0 + v1.z * n1 + v2.z * n2 + v3.z * n3;
            acc.w += v0.w * n0 + v1.w * n1 + v2.w * n2 + v3.w * n3;
        } else {
            float4 v0 = hv[(size_t)s0 * F4ROW + idx];   // s=NN -> zeroed pad row
            float4 v1 = hv[(size_t)s1 * F4ROW + idx];
            float4 v2 = hv[(size_t)s2 * F4ROW + idx];
            float4 v3 = hv[(size_t)s3 * F4ROW + idx];
            acc.x += v0.x + v1.x + v2.x + v3.x;
            acc.y += v0.y + v1.y + v2.y + v3.y;
            acc.z += v0.z + v1.z + v2.z + v3.z;
            acc.w += v0.w + v1.w + v2.w + v3.w;
        }
    }
    float ni = norm_in[n];
    float v[4] = {acc.x * ni, acc.y * ni, acc.z * ni, acc.w * ni};
    ushort hp[4], lp[4];
#pragma unroll
    for (int j = 0; j < 4; ++j) {
        _Float16 hh = (_Float16)v[j];
        _Float16 ll = (_Float16)(v[j] - (float)hh);
        hp[j] = *(ushort*)&hh;
        lp[j] = *(ushort*)&ll;
    }
    // K-tiled panel store
    int s  = (idx >= IHALF);
    int ik = idx & (IHALF - 1);
    size_t o = ((size_t)(ik >> 3) * MPAD + n * 2 + s) * 8 + (ik & 7);
    unsigned long long hv64, lv64;
    __builtin_memcpy(&hv64, hp, 8);
    __builtin_memcpy(&lv64, lp, 8);
    __builtin_nontemporal_store(hv64, (unsigned long long*)Ah + o);
    __builtin_nontemporal_store(lv64, (unsigned long long*)Al + o);
}

// ---------------- split-f16 MFMA GEMM, A-direct (r22) ----------
// Tall-skinny 40064x256x{128|256}: A consumed once per N-tile -> NO A-LDS.
// A fragments load straight global->VGPR from the K-tiled panel layout
// (1 KB fully-coalesced per wave-load); only B (W hi/lo) staged in LDS
// (20 KB -> ~4 blocks/CU, grid 626x2=1252 -> ~16-20 waves/CU vs r21's 4).
// Block 64M x 128N, 4 waves each 64M x 32N: 24 MFMA (~120cy) vs 8 B-ds_reads
// (~96cy) per K-step -> MFMA-bound. A-loads issued before B staging so their
// latency hides under stage+barrier.
// D[m,c] = relu( A[m,:] . W[:,c] + b[c] ) [* norm_out fold], acc += Ah*Wh +
// Al*Wh + Ah*Wl.
// FUSE: relu -> *fc_w -> mean_s -> 16-lane reduce -> atomicAdd(out[node], 0.5p).
template<int KP, bool FUSE>
__global__ __launch_bounds__(256) void gemm_split(const ushort* __restrict__ Ah,
                                                  const ushort* __restrict__ Al,
                                                  const ushort* __restrict__ Wh,
                                                  const ushort* __restrict__ Wl,
                                                  const float* __restrict__ b,
                                                  void* __restrict__ outv,
                                                  const float* __restrict__ fcw,
                                                  const float* __restrict__ nrm) {
    constexpr int NT = KP / 32;
    __shared__ __align__(16) _Float16 Bh_s[128][40];
    __shared__ __align__(16) _Float16 Bl_s[128][40];

    int tid  = threadIdx.x;
    int m0   = blockIdx.x * 64;
    int n0   = blockIdx.y * 128;
    int wave = tid >> 6, lane = tid & 63;
    int lr = lane & 15, quad = lane >> 4;
    int wcol = wave * 32;                  // wave's 32-col slice within n0

    f32x4 acc[4][2];
#pragma unroll
    for (int mi = 0; mi < 4; ++mi)
#pragma unroll
        for (int ni = 0; ni < 2; ++ni) acc[mi][ni] = {0.f, 0.f, 0.f, 0.f};

    const uint4* Whv = (const uint4*)Wh;   // row stride 32 uint4
    const uint4* Wlv = (const uint4*)Wl;

    for (int t0 = 0; t0 < NT; ++t0) {
        // ---- A fragments direct from global (K-tiled panel; issue FIRST)
        f16x8 ah[4], al[4];
#pragma unroll
        for (int mi = 0; mi < 4; ++mi) {
            size_t fh = ((size_t)t0 * MPAD + m0 + mi * 16 + lr) * 32 + quad * 8;
            ah[mi] = *(const f16x8*)(Ah + fh);
            al[mi] = *(const f16x8*)(Al + fh);
        }
        // ---- stage B: 128 cols x 32 k, hi+lo (2 uint4/thread each)
#pragma unroll
        for (int it = 0; it < 2; ++it) {
            int f = it * 256 + tid;
            int rn = f >> 2, q = f & 3;
            size_t base = (size_t)(n0 + rn) * 32 + t0 * 4 + q;
            *(uint4*)&Bh_s[rn][q * 8] = Whv[base];
            *(uint4*)&Bl_s[rn][q * 8] = Wlv[base];
        }
        __syncthreads();

        f16x8 bh[2], bl[2];
#pragma unroll
        for (int ni = 0; ni < 2; ++ni) {
            bh[ni] = *(const f16x8*)&Bh_s[wcol + ni * 16 + lr][quad * 8];
            bl[ni] = *(const f16x8*)&Bl_s[wcol + ni * 16 + lr][quad * 8];
        }
#pragma unroll
        for (int mi = 0; mi < 4; ++mi)
#pragma unroll
            for (int ni = 0; ni < 2; ++ni) {
                acc[mi][ni] = __builtin_amdgcn_mfma_f32_16x16x32_f16(ah[mi], bh[ni], acc[mi][ni], 0, 0, 0);
                acc[mi][ni] = __builtin_amdgcn_mfma_f32_16x16x32_f16(al[mi], bh[ni], acc[mi][ni], 0, 0, 0);
                acc[mi][ni] = __builtin_amdgcn_mfma_f32_16x16x32_f16(ah[mi], bl[ni], acc[mi][ni], 0, 0, 0);
            }
        __syncthreads();
    }

    if (FUSE) {
        float* out = (float*)outv;
#pragma unroll
        for (int mi = 0; mi < 4; ++mi) {
#pragma unroll
            for (int i = 0; i < 4; ++i) {
                float p = 0.f;
#pragma unroll
                for (int ni = 0; ni < 2; ++ni) {
                    int c = n0 + wcol + ni * 16 + lr;
                    if (c < 246)
                        p += fmaxf(acc[mi][ni][i] + b[c], 0.f) * fcw[c];
                }
#pragma unroll
                for (int off = 8; off > 0; off >>= 1)
                    p += __shfl_down(p, off, 16);
                int m = m0 + mi * 16 + quad * 4 + i;
                if (lr == 0 && m < NN * SS)
                    atomicAdd(&out[m >> 1], 0.5f * p);
            }
        }
    } else {
        float* outF = (float*)outv;    // fp32 [M][256]; cols>=246 get 0 (acc=0, bj=0)
#pragma unroll
        for (int ni = 0; ni < 2; ++ni) {
            int c = n0 + wcol + ni * 16 + lr;
            float bj = (c < 246) ? b[c] : 0.f;
#pragma unroll
            for (int mi = 0; mi < 4; ++mi)
#pragma unroll
                for (int i = 0; i < 4; ++i) {
                    int m = m0 + mi * 16 + quad * 4 + i;
                    if (m < NN * SS) {
                        float no = nrm[m >> 1];
                        outF[(size_t)m * 256 + c] = fmaxf(acc[mi][ni][i] + bj, 0.f) * no;
                    }
                }
        }
    }
}

extern "C" void kernel_launch(void* const* d_in, const int* in_sizes, int n_in,
                              void* d_out, int out_size, void* d_ws, size_t ws_size,
                              hipStream_t stream) {
    const float* feat = (const float*)d_in[0];
    const int*   src  = (const int*)d_in[1];
    const int*   dst  = (const int*)d_in[2];
    const float* W0   = (const float*)d_in[3];
    const float* b0   = (const float*)d_in[4];
    const float* W1   = (const float*)d_in[5];
    const float* b1   = (const float*)d_in[6];
    const float* W2   = (const float*)d_in[7];
    const float* b2   = (const float*)d_in[8];
    const float* fcw  = (const float*)d_in[9];
    const float* fcb  = (const float*)d_in[10];
    float* out = (float*)d_out;

    char* ws = (char*)d_ws;
    size_t off = 0;
    auto alloc = [&](size_t bytes) {
        void* p = ws + off;
        off = (off + bytes + 255) & ~(size_t)255;
        return p;
    };
    int*    deg_out_i = (int*)alloc((2 * NN + 64) * sizeof(int));
    int*    deg_in_i  = deg_out_i + NN;
    int*    counter   = deg_out_i + 2 * NN;
    int*    row_start = (int*)alloc(NN * sizeof(int));
    int*    cursor    = (int*)alloc(NN * sizeof(int));
    ushort* sorted    = (ushort*)alloc((NE + 3 * NN + 16) * sizeof(ushort));
    float*  norm_out  = (float*)alloc((NN + 1) * sizeof(float));   // [NN] = 0 (pad)
    float*  norm_in   = (float*)alloc(NN * sizeof(float));
    ushort* Wh0 = (ushort*)alloc(256 * 256 * sizeof(ushort));
    ushort* Wl0 = (ushort*)alloc(256 * 256 * sizeof(ushort));
    ushort* Wh1 = (ushort*)alloc(256 * 256 * sizeof(ushort));
    ushort* Wl1 = (ushort*)alloc(256 * 256 * sizeof(ushort));
    ushort* Wh2 = (ushort*)alloc(256 * 256 * sizeof(ushort));
    ushort* Wl2 = (ushort*)alloc(256 * 256 * sizeof(ushort));
    ushort* Ahb = (ushort*)alloc((size_t)MPAD * 256 * sizeof(ushort));  // split A hi (K-tiled)
    ushort* Alb = (ushort*)alloc((size_t)MPAD * 256 * sizeof(ushort));  // split A lo (K-tiled)
    float*  bufH = (float*)alloc(((size_t)NN * SS * 256 + 512) * sizeof(float)); // +zero pad row

    hipMemsetAsync(deg_out_i, 0, (2 * NN + 1) * sizeof(int), stream);
    hipMemsetAsync(bufH + (size_t)NN * 512, 0, 512 * sizeof(float), stream);  // pad row (src=NN)

    degree_kernel<<<(NE + 255) / 256, 256, 0, stream>>>(src, dst, deg_out_i, deg_in_i);
    alloc_kernel<<<(NN + 255) / 256, 256, 0, stream>>>(deg_out_i, deg_in_i, norm_out, norm_in,
                                                       row_start, cursor, counter);
    pad_fill<<<(NN + 255) / 256, 256, 0, stream>>>(row_start, deg_in_i, sorted);
    scatter_kernel<<<(NE + 255) / 256, 256, 0, stream>>>(src, dst, cursor, sorted);

    convert_w_all<<<dim3(256, 3), 256, 0, stream>>>(W0, W1, W2, Wh0, Wl0, Wh1, Wl1, Wh2, Wl2);
    init_out<<<(NN + 255) / 256, 256, 0, stream>>>(out, fcb, norm_out);
    zero_pads<<<16, 256, 0, stream>>>(Ahb, Alb);

    const int NB8 = (NN + 7) / 8;             // 2500 node groups (8 nodes/block)
    dim3 ggrid(MPAD / 64, 2);                 // 626 x 2 = 1252 blocks

    // Layer 0: feat [N][2*128] -> agg (norm gathers, row clamp) -> gemm(*norm_out) -> bufH
    aggregate4<64, 4, true><<<NB8 * 4, 128, 0, stream>>>(feat, row_start, deg_in_i, sorted,
                                                         norm_out, norm_in, Ahb, Alb);
    gemm_split<FIN, false><<<ggrid, 256, 0, stream>>>(Ahb, Alb, Wh0, Wl0, b0, bufH, fcw, norm_out);

    // Layer 1: bufH (pre-scaled by norm_out) -> pure-sum agg -> gemm(*norm_out) -> bufH
    aggregate4<128, 8, false><<<NB8 * 8, 128, 0, stream>>>(bufH, row_start, deg_in_i, sorted,
                                                           norm_out, norm_in, Ahb, Alb);
    gemm_split<256, false><<<ggrid, 256, 0, stream>>>(Ahb, Alb, Wh1, Wl1, b1, bufH, fcw, norm_out);

    // Layer 2: bufH -> pure-sum agg -> fused gemm -> out (atomicAdd; out pre-set to fcb)
    aggregate4<128, 8, false><<<NB8 * 8, 128, 0, stream>>>(bufH, row_start, deg_in_i, sorted,
                                                           norm_out, norm_in, Ahb, Alb);
    gemm_split<256, true><<<ggrid, 256, 0, stream>>>(Ahb, Alb, Wh2, Wl2, b2, out, fcw, norm_out);
}

// Round 6
// 388.730 us; speedup vs baseline: 1.0188x; 1.0188x over previous
//
#include <hip/hip_runtime.h>
#include <hip/hip_fp16.h>

#define NN 20000      // nodes
#define NE 320000     // edges
#define SS 2          // feature axis
#define FIN 128
#define FH 246
#define MPAD 40064    // M (=NN*SS) padded to 64

typedef _Float16 f16x8 __attribute__((ext_vector_type(8)));
typedef float f32x4 __attribute__((ext_vector_type(4)));

// ---------------- degree histogram ----------------
__global__ void degree_kernel(const int* __restrict__ src, const int* __restrict__ dst,
                              int* __restrict__ deg_out, int* __restrict__ deg_in) {
    int e = blockIdx.x * blockDim.x + threadIdx.x;
    if (e < NE) {
        atomicAdd(&deg_out[src[e]], 1);
        atomicAdd(&deg_in[dst[e]], 1);
    }
}

// ---------------- norms + parallel CSR range allocation (fused) ----------------
// ranges PADDED to multiples of 4 (pad slots get src=NN -> zero row) so the
// aggregate can do one aligned ushort4 index load per 4 edges, no tail loop.
__global__ void alloc_kernel(const int* __restrict__ deg_out, const int* __restrict__ deg_in,
                             float* __restrict__ norm_out, float* __restrict__ norm_in,
                             int* __restrict__ row_start, int* __restrict__ cursor,
                             int* __restrict__ counter) {
    __shared__ int smem[256];
    __shared__ int base_s;
    int tid = threadIdx.x;
    int i = blockIdx.x * 256 + tid;
    int v  = (i < NN) ? deg_in[i] : 0;
    int vp = (v + 3) & ~3;                 // padded degree
    smem[tid] = vp;
    __syncthreads();
    for (int off = 1; off < 256; off <<= 1) {
        int t = (tid >= off) ? smem[tid - off] : 0;
        __syncthreads();
        smem[tid] += t;
        __syncthreads();
    }
    int incl = smem[tid];
    if (tid == 0) base_s = atomicAdd(counter, smem[255]);
    __syncthreads();
    if (i < NN) {
        int excl = base_s + incl - vp;     // multiple of 4 by construction
        row_start[i] = excl;
        cursor[i]    = excl;
        norm_out[i] = rsqrtf(fmaxf((float)deg_out[i], 1.0f));
        norm_in[i]  = rsqrtf(fmaxf((float)v, 1.0f));
    }
}

// ---------------- scatter edges into CSR (ushort indices: NN < 65536) ----------
__global__ void scatter_kernel(const int* __restrict__ src, const int* __restrict__ dst,
                               int* __restrict__ cursor, ushort* __restrict__ sorted_src) {
    int e = blockIdx.x * blockDim.x + threadIdx.x;
    if (e < NE) {
        int d = dst[e];
        int pos = atomicAdd(&cursor[d], 1);
        sorted_src[pos] = (ushort)src[e];
    }
}

// ---------------- fill pad slots with src=NN (the zero/dead row) ----------------
__global__ void pad_fill(const int* __restrict__ row_start, const int* __restrict__ deg_in,
                         ushort* __restrict__ sorted_src) {
    int n = blockIdx.x * 256 + threadIdx.x;
    if (n < NN) {
        int d = deg_in[n];
        int beg = row_start[n] + d;
        int end = row_start[n] + ((d + 3) & ~3);
        for (int p = beg; p < end; ++p) sorted_src[p] = (ushort)NN;
    }
}

// ---------------- W pre-split, FRAG-PACKED (r23) ----------------
// Layout: half at ((c16*8 + kt)*64 + quad*16 + lr)*8 + j, where the GEMM wave's
// lane (quad,lr) loads fragment (c16,kt) at offset lane*8 -> every B-frag load
// is one fully-coalesced 1 KB wave-load. kt slots fixed at 8 (KP=128 reads
// kt<4; 4..7 hold zeros). Zero-pad n>=246 / k>=K as before.
__global__ void convert_w_all(const float* __restrict__ W0, const float* __restrict__ W1,
                              const float* __restrict__ W2,
                              ushort* __restrict__ Wh0, ushort* __restrict__ Wl0,
                              ushort* __restrict__ Wh1, ushort* __restrict__ Wl1,
                              ushort* __restrict__ Wh2, ushort* __restrict__ Wl2) {
    int n = blockIdx.x, k = threadIdx.x;
    const float* W; ushort* Wh; ushort* Wl; int K;
    if (blockIdx.y == 0)      { W = W0; Wh = Wh0; Wl = Wl0; K = FIN; }
    else if (blockIdx.y == 1) { W = W1; Wh = Wh1; Wl = Wl1; K = FH; }
    else                      { W = W2; Wh = Wh2; Wl = Wl2; K = FH; }
    float v = (k < K && n < 246) ? W[k * 246 + n] : 0.f;
    _Float16 h = (_Float16)v;
    _Float16 l = (_Float16)(v - (float)h);
    int c16 = n >> 4, lr = n & 15, kt = k >> 5, quad = (k >> 3) & 3, j = k & 7;
    int off = ((c16 * 8 + kt) * 64 + quad * 16 + lr) * 8 + j;
    Wh[off] = *(ushort*)&h;
    Wl[off] = *(ushort*)&l;
}

__global__ void init_out(float* __restrict__ out, const float* __restrict__ fcb,
                         float* __restrict__ norm_out) {
    int i = blockIdx.x * 256 + threadIdx.x;
    if (i < NN) out[i] = fcb[0];
    if (i == 0) norm_out[NN] = 0.f;   // dead-norm entry for layer-0 pad edges
}

// ---------------- zero the M-pad rows of the K-tiled A buffers ----------------
// A_tiled layout: half at (kt*MPAD + m)*32 + kk, kt<8, pads m in [40000,40064).
__global__ void zero_pads(ushort* __restrict__ Ah, ushort* __restrict__ Al) {
    int i = blockIdx.x * 256 + threadIdx.x;        // 4096 ull per buffer
    if (i < 4096) {
        int kt = i >> 9, r = i & 511;
        int m = NN * SS + (r >> 3), j = r & 7;
        size_t o = ((size_t)kt * MPAD + m) * 8 + j;
        ((unsigned long long*)Ah)[o] = 0ull;
        ((unsigned long long*)Al)[o] = 0ull;
    }
}

// ---------------- XCD-pinned chunk-tiled gather-aggregate, split-f16 output ----------
// K-TILED PANEL output [K/32][MPAD][32] halfs (GEMM reads A coalesced direct).
// r21 index prefetch + nontemporal stores; r18-proven geometry (16 lanes/node,
// 256B chunks, 4 nodes/wave). Pure segment-sum (norms folded into producer);
// ushort4 packed indices, ranges 4-padded (pad src=NN -> zero row).
// NORM=true only for layer 0 (feat can't be prescaled in-place).
template<int F4ROW, int NCH, bool NORM>
__global__ void aggregate4(const float* __restrict__ h,
                           const int* __restrict__ row_start,
                           const int* __restrict__ deg_in,
                           const ushort* __restrict__ sorted_src,
                           const float* __restrict__ norm_out,
                           const float* __restrict__ norm_in,
                           ushort* __restrict__ Ah, ushort* __restrict__ Al) {
    constexpr int IHALF = F4ROW / 2;
    int g  = threadIdx.x >> 4;              // 0..7: node sub-index
    int l  = threadIdx.x & 15;              // float4 within chunk
    int cb = blockIdx.x & (NCH - 1);        // chunk (XCD-pinned axis)
    int nb = blockIdx.x / NCH;              // node group
    int n  = nb * 8 + g;
    if (n >= NN) return;
    int idx = cb * 16 + l;                  // < F4ROW (= NCH*16)
    const float4* hv = (const float4*)h;
    int beg = row_start[n];
    int end = beg + ((deg_in[n] + 3) & ~3);
    float4 acc = {0.f, 0.f, 0.f, 0.f};
    ushort4 ss;
    if (beg < end) ss = *(const ushort4*)&sorted_src[beg];   // 8B aligned (beg%4==0)
    for (int i = beg; i < end; i += 4) {
        ushort4 cur = ss;
        if (i + 4 < end) ss = *(const ushort4*)&sorted_src[i + 4];   // prefetch
        int s0 = cur.x, s1 = cur.y, s2 = cur.z, s3 = cur.w;
        if (NORM) {
            float n0 = norm_out[s0], n1 = norm_out[s1];
            float n2 = norm_out[s2], n3 = norm_out[s3];
            float4 v0 = hv[(size_t)(s0 < NN ? s0 : NN - 1) * F4ROW + idx];
            float4 v1 = hv[(size_t)(s1 < NN ? s1 : NN - 1) * F4ROW + idx];
            float4 v2 = hv[(size_t)(s2 < NN ? s2 : NN - 1) * F4ROW + idx];
            float4 v3 = hv[(size_t)(s3 < NN ? s3 : NN - 1) * F4ROW + idx];
            acc.x += v0.x * n0 + v1.x * n1 + v2.x * n2 + v3.x * n3;
            acc.y += v0.y * n0 + v1.y * n1 + v2.y * n2 + v3.y * n3;
            acc.z += v0.z * n0 + v1.z * n1 + v2.z * n2 + v3.z * n3;
            acc.w += v0.w * n0 + v1.w * n1 + v2.w * n2 + v3.w * n3;
        } else {
            float4 v0 = hv[(size_t)s0 * F4ROW + idx];   // s=NN -> zeroed pad row
            float4 v1 = hv[(size_t)s1 * F4ROW + idx];
            float4 v2 = hv[(size_t)s2 * F4ROW + idx];
            float4 v3 = hv[(size_t)s3 * F4ROW + idx];
            acc.x += v0.x + v1.x + v2.x + v3.x;
            acc.y += v0.y + v1.y + v2.y + v3.y;
            acc.z += v0.z + v1.z + v2.z + v3.z;
            acc.w += v0.w + v1.w + v2.w + v3.w;
        }
    }
    float ni = norm_in[n];
    float v[4] = {acc.x * ni, acc.y * ni, acc.z * ni, acc.w * ni};
    ushort hp[4], lp[4];
#pragma unroll
    for (int j = 0; j < 4; ++j) {
        _Float16 hh = (_Float16)v[j];
        _Float16 ll = (_Float16)(v[j] - (float)hh);
        hp[j] = *(ushort*)&hh;
        lp[j] = *(ushort*)&ll;
    }
    // K-tiled panel store
    int s  = (idx >= IHALF);
    int ik = idx & (IHALF - 1);
    size_t o = ((size_t)(ik >> 3) * MPAD + n * 2 + s) * 8 + (ik & 7);
    unsigned long long hv64, lv64;
    __builtin_memcpy(&hv64, hp, 8);
    __builtin_memcpy(&lv64, lp, 8);
    __builtin_nontemporal_store(hv64, (unsigned long long*)Ah + o);
    __builtin_nontemporal_store(lv64, (unsigned long long*)Al + o);
}

// ---------------- split-f16 MFMA GEMM, B-STATIONARY IN VGPRS (r23) ----------
// r21/r22 lesson: dur invariant ~56us across LDS structures, MfmaUtil 10% --
// the per-K-step __syncthreads forces a vmcnt(0) drain of the A stream every
// step. Fix: NO LDS, NO BARRIERS. Each wave holds its 32-col B slice (hi+lo)
// in 128 VGPRs, loaded once from the frag-packed W (32 coalesced 1KB loads,
// L2-resident). Main loop (fully unrolled): 16 coalesced A-loads + 24 MFMA per
// K-step; compiler pipelines A-loads across steps with counted vmcnt.
// Block 64M x 128N, 4 waves each 64M x 32N. ~240 VGPR -> 2 waves/SIMD.
// D[m,c] = relu( A[m,:] . W[:,c] + b[c] ) [* norm_out fold], acc += Ah*Wh +
// Al*Wh + Ah*Wl.
// FUSE: relu -> *fc_w -> mean_s -> 16-lane reduce -> atomicAdd(out[node], 0.5p).
template<int KP, bool FUSE>
__global__ __launch_bounds__(256, 1) void gemm_breg(const ushort* __restrict__ Ah,
                                                    const ushort* __restrict__ Al,
                                                    const ushort* __restrict__ Whp,
                                                    const ushort* __restrict__ Wlp,
                                                    const float* __restrict__ b,
                                                    void* __restrict__ outv,
                                                    const float* __restrict__ fcw,
                                                    const float* __restrict__ nrm) {
    constexpr int NT = KP / 32;
    int tid  = threadIdx.x;
    int m0   = blockIdx.x * 64;
    int n0   = blockIdx.y * 128;
    int wave = tid >> 6, lane = tid & 63;
    int lr = lane & 15, quad = lane >> 4;
    int wcol = wave * 32;                  // wave's 32-col slice within n0
    int c0 = (n0 + wcol) >> 4;             // first col-tile (16-col) index

    // ---- B fragments resident in VGPRs (one coalesced 1KB load each)
    f16x8 bh[2][NT], bl[2][NT];
#pragma unroll
    for (int ni = 0; ni < 2; ++ni)
#pragma unroll
        for (int kt = 0; kt < NT; ++kt) {
            size_t o = ((size_t)((c0 + ni) * 8 + kt) * 64 + lane) * 8;
            bh[ni][kt] = *(const f16x8*)(Whp + o);
            bl[ni][kt] = *(const f16x8*)(Wlp + o);
        }

    f32x4 acc[4][2];
#pragma unroll
    for (int mi = 0; mi < 4; ++mi)
#pragma unroll
        for (int ni = 0; ni < 2; ++ni) acc[mi][ni] = {0.f, 0.f, 0.f, 0.f};

    // ---- barrier-free streaming K-loop
#pragma unroll
    for (int t0 = 0; t0 < NT; ++t0) {
        f16x8 ah[4], al[4];
#pragma unroll
        for (int mi = 0; mi < 4; ++mi) {
            size_t fh = ((size_t)t0 * MPAD + m0 + mi * 16 + lr) * 32 + quad * 8;
            ah[mi] = *(const f16x8*)(Ah + fh);
            al[mi] = *(const f16x8*)(Al + fh);
        }
#pragma unroll
        for (int mi = 0; mi < 4; ++mi)
#pragma unroll
            for (int ni = 0; ni < 2; ++ni) {
                acc[mi][ni] = __builtin_amdgcn_mfma_f32_16x16x32_f16(ah[mi], bh[ni][t0], acc[mi][ni], 0, 0, 0);
                acc[mi][ni] = __builtin_amdgcn_mfma_f32_16x16x32_f16(al[mi], bh[ni][t0], acc[mi][ni], 0, 0, 0);
                acc[mi][ni] = __builtin_amdgcn_mfma_f32_16x16x32_f16(ah[mi], bl[ni][t0], acc[mi][ni], 0, 0, 0);
            }
    }

    if (FUSE) {
        float* out = (float*)outv;
#pragma unroll
        for (int mi = 0; mi < 4; ++mi) {
#pragma unroll
            for (int i = 0; i < 4; ++i) {
                float p = 0.f;
#pragma unroll
                for (int ni = 0; ni < 2; ++ni) {
                    int c = n0 + wcol + ni * 16 + lr;
                    if (c < 246)
                        p += fmaxf(acc[mi][ni][i] + b[c], 0.f) * fcw[c];
                }
#pragma unroll
                for (int off = 8; off > 0; off >>= 1)
                    p += __shfl_down(p, off, 16);
                int m = m0 + mi * 16 + quad * 4 + i;
                if (lr == 0 && m < NN * SS)
                    atomicAdd(&out[m >> 1], 0.5f * p);
            }
        }
    } else {
        float* outF = (float*)outv;    // fp32 [M][256]; cols>=246 get 0 (acc=0, bj=0)
#pragma unroll
        for (int ni = 0; ni < 2; ++ni) {
            int c = n0 + wcol + ni * 16 + lr;
            float bj = (c < 246) ? b[c] : 0.f;
#pragma unroll
            for (int mi = 0; mi < 4; ++mi)
#pragma unroll
                for (int i = 0; i < 4; ++i) {
                    int m = m0 + mi * 16 + quad * 4 + i;
                    if (m < NN * SS) {
                        float no = nrm[m >> 1];
                        outF[(size_t)m * 256 + c] = fmaxf(acc[mi][ni][i] + bj, 0.f) * no;
                    }
                }
        }
    }
}

extern "C" void kernel_launch(void* const* d_in, const int* in_sizes, int n_in,
                              void* d_out, int out_size, void* d_ws, size_t ws_size,
                              hipStream_t stream) {
    const float* feat = (const float*)d_in[0];
    const int*   src  = (const int*)d_in[1];
    const int*   dst  = (const int*)d_in[2];
    const float* W0   = (const float*)d_in[3];
    const float* b0   = (const float*)d_in[4];
    const float* W1   = (const float*)d_in[5];
    const float* b1   = (const float*)d_in[6];
    const float* W2   = (const float*)d_in[7];
    const float* b2   = (const float*)d_in[8];
    const float* fcw  = (const float*)d_in[9];
    const float* fcb  = (const float*)d_in[10];
    float* out = (float*)d_out;

    char* ws = (char*)d_ws;
    size_t off = 0;
    auto alloc = [&](size_t bytes) {
        void* p = ws + off;
        off = (off + bytes + 255) & ~(size_t)255;
        return p;
    };
    int*    deg_out_i = (int*)alloc((2 * NN + 64) * sizeof(int));
    int*    deg_in_i  = deg_out_i + NN;
    int*    counter   = deg_out_i + 2 * NN;
    int*    row_start = (int*)alloc(NN * sizeof(int));
    int*    cursor    = (int*)alloc(NN * sizeof(int));
    ushort* sorted    = (ushort*)alloc((NE + 3 * NN + 16) * sizeof(ushort));
    float*  norm_out  = (float*)alloc((NN + 1) * sizeof(float));   // [NN] = 0 (pad)
    float*  norm_in   = (float*)alloc(NN * sizeof(float));
    ushort* Wh0 = (ushort*)alloc(256 * 256 * sizeof(ushort));
    ushort* Wl0 = (ushort*)alloc(256 * 256 * sizeof(ushort));
    ushort* Wh1 = (ushort*)alloc(256 * 256 * sizeof(ushort));
    ushort* Wl1 = (ushort*)alloc(256 * 256 * sizeof(ushort));
    ushort* Wh2 = (ushort*)alloc(256 * 256 * sizeof(ushort));
    ushort* Wl2 = (ushort*)alloc(256 * 256 * sizeof(ushort));
    ushort* Ahb = (ushort*)alloc((size_t)MPAD * 256 * sizeof(ushort));  // split A hi (K-tiled)
    ushort* Alb = (ushort*)alloc((size_t)MPAD * 256 * sizeof(ushort));  // split A lo (K-tiled)
    float*  bufH = (float*)alloc(((size_t)NN * SS * 256 + 512) * sizeof(float)); // +zero pad row

    hipMemsetAsync(deg_out_i, 0, (2 * NN + 1) * sizeof(int), stream);
    hipMemsetAsync(bufH + (size_t)NN * 512, 0, 512 * sizeof(float), stream);  // pad row (src=NN)

    degree_kernel<<<(NE + 255) / 256, 256, 0, stream>>>(src, dst, deg_out_i, deg_in_i);
    alloc_kernel<<<(NN + 255) / 256, 256, 0, stream>>>(deg_out_i, deg_in_i, norm_out, norm_in,
                                                       row_start, cursor, counter);
    pad_fill<<<(NN + 255) / 256, 256, 0, stream>>>(row_start, deg_in_i, sorted);
    scatter_kernel<<<(NE + 255) / 256, 256, 0, stream>>>(src, dst, cursor, sorted);

    convert_w_all<<<dim3(256, 3), 256, 0, stream>>>(W0, W1, W2, Wh0, Wl0, Wh1, Wl1, Wh2, Wl2);
    init_out<<<(NN + 255) / 256, 256, 0, stream>>>(out, fcb, norm_out);
    zero_pads<<<16, 256, 0, stream>>>(Ahb, Alb);

    const int NB8 = (NN + 7) / 8;             // 2500 node groups (8 nodes/block)
    dim3 ggrid(MPAD / 64, 2);                 // 626 x 2 = 1252 blocks

    // Layer 0: feat [N][2*128] -> agg (norm gathers, row clamp) -> gemm(*norm_out) -> bufH
    aggregate4<64, 4, true><<<NB8 * 4, 128, 0, stream>>>(feat, row_start, deg_in_i, sorted,
                                                         norm_out, norm_in, Ahb, Alb);
    gemm_breg<FIN, false><<<ggrid, 256, 0, stream>>>(Ahb, Alb, Wh0, Wl0, b0, bufH, fcw, norm_out);

    // Layer 1: bufH (pre-scaled by norm_out) -> pure-sum agg -> gemm(*norm_out) -> bufH
    aggregate4<128, 8, false><<<NB8 * 8, 128, 0, stream>>>(bufH, row_start, deg_in_i, sorted,
                                                           norm_out, norm_in, Ahb, Alb);
    gemm_breg<256, false><<<ggrid, 256, 0, stream>>>(Ahb, Alb, Wh1, Wl1, b1, bufH, fcw, norm_out);

    // Layer 2: bufH -> pure-sum agg -> fused gemm -> out (atomicAdd; out pre-set to fcb)
    aggregate4<128, 8, false><<<NB8 * 8, 128, 0, stream>>>(bufH, row_start, deg_in_i, sorted,
                                                           norm_out, norm_in, Ahb, Alb);
    gemm_breg<256, true><<<ggrid, 256, 0, stream>>>(Ahb, Alb, Wh2, Wl2, b2, out, fcw, norm_out);
}

// Round 7
// 353.831 us; speedup vs baseline: 1.1192x; 1.0986x over previous
//
#include <hip/hip_runtime.h>
#include <hip/hip_fp16.h>

#define NN 20000      // nodes
#define NE 320000     // edges
#define SS 2          // feature axis
#define FIN 128
#define FH 246
#define MPAD 40064    // M (=NN*SS) padded to 64

typedef _Float16 f16x8 __attribute__((ext_vector_type(8)));
typedef float f32x4 __attribute__((ext_vector_type(4)));

// ---------------- degree histogram ----------------
__global__ void degree_kernel(const int* __restrict__ src, const int* __restrict__ dst,
                              int* __restrict__ deg_out, int* __restrict__ deg_in) {
    int e = blockIdx.x * blockDim.x + threadIdx.x;
    if (e < NE) {
        atomicAdd(&deg_out[src[e]], 1);
        atomicAdd(&deg_in[dst[e]], 1);
    }
}

// ---------------- norms + parallel CSR range allocation (fused) ----------------
// ranges PADDED to multiples of 4 (pad slots get src=NN -> zero row) so the
// aggregate can do one aligned ushort4 index load per 4 edges, no tail loop.
__global__ void alloc_kernel(const int* __restrict__ deg_out, const int* __restrict__ deg_in,
                             float* __restrict__ norm_out, float* __restrict__ norm_in,
                             int* __restrict__ row_start, int* __restrict__ cursor,
                             int* __restrict__ counter) {
    __shared__ int smem[256];
    __shared__ int base_s;
    int tid = threadIdx.x;
    int i = blockIdx.x * 256 + tid;
    int v  = (i < NN) ? deg_in[i] : 0;
    int vp = (v + 3) & ~3;                 // padded degree
    smem[tid] = vp;
    __syncthreads();
    for (int off = 1; off < 256; off <<= 1) {
        int t = (tid >= off) ? smem[tid - off] : 0;
        __syncthreads();
        smem[tid] += t;
        __syncthreads();
    }
    int incl = smem[tid];
    if (tid == 0) base_s = atomicAdd(counter, smem[255]);
    __syncthreads();
    if (i < NN) {
        int excl = base_s + incl - vp;     // multiple of 4 by construction
        row_start[i] = excl;
        cursor[i]    = excl;
        norm_out[i] = rsqrtf(fmaxf((float)deg_out[i], 1.0f));
        norm_in[i]  = rsqrtf(fmaxf((float)v, 1.0f));
    }
}

// ---------------- scatter edges into CSR (ushort indices: NN < 65536) ----------
__global__ void scatter_kernel(const int* __restrict__ src, const int* __restrict__ dst,
                               int* __restrict__ cursor, ushort* __restrict__ sorted_src) {
    int e = blockIdx.x * blockDim.x + threadIdx.x;
    if (e < NE) {
        int d = dst[e];
        int pos = atomicAdd(&cursor[d], 1);
        sorted_src[pos] = (ushort)src[e];
    }
}

// ---------------- fill pad slots with src=NN (the zero/dead row) ----------------
__global__ void pad_fill(const int* __restrict__ row_start, const int* __restrict__ deg_in,
                         ushort* __restrict__ sorted_src) {
    int n = blockIdx.x * 256 + threadIdx.x;
    if (n < NN) {
        int d = deg_in[n];
        int beg = row_start[n] + d;
        int end = row_start[n] + ((d + 3) & ~3);
        for (int p = beg; p < end; ++p) sorted_src[p] = (ushort)NN;
    }
}

// ---------------- W pre-split, FRAG-PACKED ----------------
// Layout: half at ((c16*8 + kt)*64 + quad*16 + lr)*8 + j -> every B-frag load
// in the GEMM is one fully-coalesced 1 KB wave-load (lane*16B). kt slots fixed
// at 8 (KP=128 reads kt<4; 4..7 hold zeros). Zero-pad n>=246 / k>=K.
__global__ void convert_w_all(const float* __restrict__ W0, const float* __restrict__ W1,
                              const float* __restrict__ W2,
                              ushort* __restrict__ Wh0, ushort* __restrict__ Wl0,
                              ushort* __restrict__ Wh1, ushort* __restrict__ Wl1,
                              ushort* __restrict__ Wh2, ushort* __restrict__ Wl2) {
    int n = blockIdx.x, k = threadIdx.x;
    const float* W; ushort* Wh; ushort* Wl; int K;
    if (blockIdx.y == 0)      { W = W0; Wh = Wh0; Wl = Wl0; K = FIN; }
    else if (blockIdx.y == 1) { W = W1; Wh = Wh1; Wl = Wl1; K = FH; }
    else                      { W = W2; Wh = Wh2; Wl = Wl2; K = FH; }
    float v = (k < K && n < 246) ? W[k * 246 + n] : 0.f;
    _Float16 h = (_Float16)v;
    _Float16 l = (_Float16)(v - (float)h);
    int c16 = n >> 4, lr = n & 15, kt = k >> 5, quad = (k >> 3) & 3, j = k & 7;
    int off = ((c16 * 8 + kt) * 64 + quad * 16 + lr) * 8 + j;
    Wh[off] = *(ushort*)&h;
    Wl[off] = *(ushort*)&l;
}

__global__ void init_out(float* __restrict__ out, const float* __restrict__ fcb,
                         float* __restrict__ norm_out) {
    int i = blockIdx.x * 256 + threadIdx.x;
    if (i < NN) out[i] = fcb[0];
    if (i == 0) norm_out[NN] = 0.f;   // dead-norm entry for layer-0 pad edges
}

// ---------------- zero the M-pad rows of the K-tiled A buffers ----------------
// A_tiled layout: half at (kt*MPAD + m)*32 + kk, kt<8, pads m in [40000,40064).
__global__ void zero_pads(ushort* __restrict__ Ah, ushort* __restrict__ Al) {
    int i = blockIdx.x * 256 + threadIdx.x;        // 4096 ull per buffer
    if (i < 4096) {
        int kt = i >> 9, r = i & 511;
        int m = NN * SS + (r >> 3), j = r & 7;
        size_t o = ((size_t)kt * MPAD + m) * 8 + j;
        ((unsigned long long*)Ah)[o] = 0ull;
        ((unsigned long long*)Al)[o] = 0ull;
    }
}

// ---------------- XCD-pinned chunk-tiled gather-aggregate, split-f16 output ----------
// K-TILED PANEL output [K/32][MPAD][32] halfs (GEMM reads A coalesced direct).
// r24: NT stores REVERTED to regular stores -- NT pushed A to HBM, so the GEMM
// paid ~900cyc/load instead of L2 ~200cyc (r20, pre-NT, had the fastest gemm).
// r21 index prefetch kept; r18-proven geometry (16 lanes/node, 256B chunks,
// 4 nodes/wave). Pure segment-sum (norms folded into producer); ushort4 packed
// indices, ranges 4-padded (pad src=NN -> zero row). NORM=true only layer 0.
template<int F4ROW, int NCH, bool NORM>
__global__ void aggregate4(const float* __restrict__ h,
                           const int* __restrict__ row_start,
                           const int* __restrict__ deg_in,
                           const ushort* __restrict__ sorted_src,
                           const float* __restrict__ norm_out,
                           const float* __restrict__ norm_in,
                           ushort* __restrict__ Ah, ushort* __restrict__ Al) {
    constexpr int IHALF = F4ROW / 2;
    int g  = threadIdx.x >> 4;              // 0..7: node sub-index
    int l  = threadIdx.x & 15;              // float4 within chunk
    int cb = blockIdx.x & (NCH - 1);        // chunk (XCD-pinned axis)
    int nb = blockIdx.x / NCH;              // node group
    int n  = nb * 8 + g;
    if (n >= NN) return;
    int idx = cb * 16 + l;                  // < F4ROW (= NCH*16)
    const float4* hv = (const float4*)h;
    int beg = row_start[n];
    int end = beg + ((deg_in[n] + 3) & ~3);
    float4 acc = {0.f, 0.f, 0.f, 0.f};
    ushort4 ss;
    if (beg < end) ss = *(const ushort4*)&sorted_src[beg];   // 8B aligned (beg%4==0)
    for (int i = beg; i < end; i += 4) {
        ushort4 cur = ss;
        if (i + 4 < end) ss = *(const ushort4*)&sorted_src[i + 4];   // prefetch
        int s0 = cur.x, s1 = cur.y, s2 = cur.z, s3 = cur.w;
        if (NORM) {
            float n0 = norm_out[s0], n1 = norm_out[s1];
            float n2 = norm_out[s2], n3 = norm_out[s3];
            float4 v0 = hv[(size_t)(s0 < NN ? s0 : NN - 1) * F4ROW + idx];
            float4 v1 = hv[(size_t)(s1 < NN ? s1 : NN - 1) * F4ROW + idx];
            float4 v2 = hv[(size_t)(s2 < NN ? s2 : NN - 1) * F4ROW + idx];
            float4 v3 = hv[(size_t)(s3 < NN ? s3 : NN - 1) * F4ROW + idx];
            acc.x += v0.x * n0 + v1.x * n1 + v2.x * n2 + v3.x * n3;
            acc.y += v0.y * n0 + v1.y * n1 + v2.y * n2 + v3.y * n3;
            acc.z += v0.z * n0 + v1.z * n1 + v2.z * n2 + v3.z * n3;
            acc.w += v0.w * n0 + v1.w * n1 + v2.w * n2 + v3.w * n3;
        } else {
            float4 v0 = hv[(size_t)s0 * F4ROW + idx];   // s=NN -> zeroed pad row
            float4 v1 = hv[(size_t)s1 * F4ROW + idx];
            float4 v2 = hv[(size_t)s2 * F4ROW + idx];
            float4 v3 = hv[(size_t)s3 * F4ROW + idx];
            acc.x += v0.x + v1.x + v2.x + v3.x;
            acc.y += v0.y + v1.y + v2.y + v3.y;
            acc.z += v0.z + v1.z + v2.z + v3.z;
            acc.w += v0.w + v1.w + v2.w + v3.w;
        }
    }
    float ni = norm_in[n];
    float v[4] = {acc.x * ni, acc.y * ni, acc.z * ni, acc.w * ni};
    ushort hp[4], lp[4];
#pragma unroll
    for (int j = 0; j < 4; ++j) {
        _Float16 hh = (_Float16)v[j];
        _Float16 ll = (_Float16)(v[j] - (float)hh);
        hp[j] = *(ushort*)&hh;
        lp[j] = *(ushort*)&ll;
    }
    // K-tiled panel store (regular stores -> stays L2-resident for the GEMM)
    int s  = (idx >= IHALF);
    int ik = idx & (IHALF - 1);
    size_t o = ((size_t)(ik >> 3) * MPAD + n * 2 + s) * 8 + (ik & 7);
    ((unsigned long long*)Ah)[o] = *(unsigned long long*)hp;
    ((unsigned long long*)Al)[o] = *(unsigned long long*)lp;
}

// ---------------- split-f16 MFMA GEMM, streaming 2-deep pipeline (r24) ----------
// r21-r23 lesson: ~55us invariant across LDS/B-reg structures; r23's VGPR=60
// showed the compiler couldn't pipeline (B hogged the file / allocator bailed).
// r24: NO LDS, NO barriers, and BOTH A and B stream with an explicit 2-deep
// static double-buffer: loads for step t+1 issue before step t's MFMAs, so
// counted vmcnt keeps 16 loads in flight. Wave tile 32M x 64N (block 64M x
// 128N, 4 waves 2x2): per step 8 A-loads + 8 B-loads (all 1KB coalesced;
// A from K-tiled panel in L2, B frag-packed in L2) + 24 MFMA.
// D[m,c] = relu( A[m,:] . W[:,c] + b[c] ) [* norm_out fold], acc += Ah*Wh +
// Al*Wh + Ah*Wl.
// FUSE: relu -> *fc_w -> mean_s -> 16-lane reduce -> atomicAdd(out[node], 0.5p).
#define LOAD_A(T, AH, AL)                                                        \
    _Pragma("unroll")                                                            \
    for (int mi = 0; mi < 2; ++mi) {                                             \
        size_t fh = ((size_t)(T) * MPAD + m0 + wm * 32 + mi * 16 + lr) * 32 + quad * 8; \
        AH[mi] = *(const f16x8*)(Ah + fh);                                       \
        AL[mi] = *(const f16x8*)(Al + fh);                                       \
    }
#define LOAD_B(T, BH, BL)                                                        \
    _Pragma("unroll")                                                            \
    for (int ni = 0; ni < 4; ++ni) {                                             \
        size_t o = ((size_t)((c0 + ni) * 8 + (T)) * 64 + lane) * 8;              \
        BH[ni] = *(const f16x8*)(Whp + o);                                       \
        BL[ni] = *(const f16x8*)(Wlp + o);                                       \
    }
#define DO_MFMA(AH, AL, BH, BL)                                                  \
    _Pragma("unroll")                                                            \
    for (int mi = 0; mi < 2; ++mi)                                               \
        _Pragma("unroll")                                                        \
        for (int ni = 0; ni < 4; ++ni) {                                         \
            acc[mi][ni] = __builtin_amdgcn_mfma_f32_16x16x32_f16(AH[mi], BH[ni], acc[mi][ni], 0, 0, 0); \
            acc[mi][ni] = __builtin_amdgcn_mfma_f32_16x16x32_f16(AL[mi], BH[ni], acc[mi][ni], 0, 0, 0); \
            acc[mi][ni] = __builtin_amdgcn_mfma_f32_16x16x32_f16(AH[mi], BL[ni], acc[mi][ni], 0, 0, 0); \
        }

template<int KP, bool FUSE>
__global__ __launch_bounds__(256, 2) void gemm_pipe(const ushort* __restrict__ Ah,
                                                    const ushort* __restrict__ Al,
                                                    const ushort* __restrict__ Whp,
                                                    const ushort* __restrict__ Wlp,
                                                    const float* __restrict__ b,
                                                    void* __restrict__ outv,
                                                    const float* __restrict__ fcw,
                                                    const float* __restrict__ nrm) {
    constexpr int NT = KP / 32;
    int tid  = threadIdx.x;
    int m0   = blockIdx.x * 64;
    int n0   = blockIdx.y * 128;
    int wave = tid >> 6, lane = tid & 63;
    int wm = wave >> 1, wn = wave & 1;
    int lr = lane & 15, quad = lane >> 4;
    int c0 = (n0 + wn * 64) >> 4;          // first 16-col tile index

    f32x4 acc[2][4];
#pragma unroll
    for (int mi = 0; mi < 2; ++mi)
#pragma unroll
        for (int ni = 0; ni < 4; ++ni) acc[mi][ni] = {0.f, 0.f, 0.f, 0.f};

    f16x8 a0h[2], a0l[2], b0h[4], b0l[4];
    f16x8 a1h[2], a1l[2], b1h[4], b1l[4];
    LOAD_A(0, a0h, a0l)
    LOAD_B(0, b0h, b0l)
#pragma unroll
    for (int t = 0; t < NT; ++t) {
        if (t & 1) {
            if (t + 1 < NT) { LOAD_A(t + 1, a0h, a0l) LOAD_B(t + 1, b0h, b0l) }
            DO_MFMA(a1h, a1l, b1h, b1l)
        } else {
            if (t + 1 < NT) { LOAD_A(t + 1, a1h, a1l) LOAD_B(t + 1, b1h, b1l) }
            DO_MFMA(a0h, a0l, b0h, b0l)
        }
    }

    if (FUSE) {
        float* out = (float*)outv;
#pragma unroll
        for (int mi = 0; mi < 2; ++mi) {
#pragma unroll
            for (int i = 0; i < 4; ++i) {
                float p = 0.f;
#pragma unroll
                for (int ni = 0; ni < 4; ++ni) {
                    int c = n0 + wn * 64 + ni * 16 + lr;
                    if (c < 246)
                        p += fmaxf(acc[mi][ni][i] + b[c], 0.f) * fcw[c];
                }
#pragma unroll
                for (int off = 8; off > 0; off >>= 1)
                    p += __shfl_down(p, off, 16);
                int m = m0 + wm * 32 + mi * 16 + quad * 4 + i;
                if (lr == 0 && m < NN * SS)
                    atomicAdd(&out[m >> 1], 0.5f * p);
            }
        }
    } else {
        float* outF = (float*)outv;    // fp32 [M][256]; cols>=246 get 0 (acc=0, bj=0)
#pragma unroll
        for (int ni = 0; ni < 4; ++ni) {
            int c = n0 + wn * 64 + ni * 16 + lr;
            float bj = (c < 246) ? b[c] : 0.f;
#pragma unroll
            for (int mi = 0; mi < 2; ++mi)
#pragma unroll
                for (int i = 0; i < 4; ++i) {
                    int m = m0 + wm * 32 + mi * 16 + quad * 4 + i;
                    if (m < NN * SS) {
                        float no = nrm[m >> 1];
                        outF[(size_t)m * 256 + c] = fmaxf(acc[mi][ni][i] + bj, 0.f) * no;
                    }
                }
        }
    }
}

extern "C" void kernel_launch(void* const* d_in, const int* in_sizes, int n_in,
                              void* d_out, int out_size, void* d_ws, size_t ws_size,
                              hipStream_t stream) {
    const float* feat = (const float*)d_in[0];
    const int*   src  = (const int*)d_in[1];
    const int*   dst  = (const int*)d_in[2];
    const float* W0   = (const float*)d_in[3];
    const float* b0   = (const float*)d_in[4];
    const float* W1   = (const float*)d_in[5];
    const float* b1   = (const float*)d_in[6];
    const float* W2   = (const float*)d_in[7];
    const float* b2   = (const float*)d_in[8];
    const float* fcw  = (const float*)d_in[9];
    const float* fcb  = (const float*)d_in[10];
    float* out = (float*)d_out;

    char* ws = (char*)d_ws;
    size_t off = 0;
    auto alloc = [&](size_t bytes) {
        void* p = ws + off;
        off = (off + bytes + 255) & ~(size_t)255;
        return p;
    };
    int*    deg_out_i = (int*)alloc((2 * NN + 64) * sizeof(int));
    int*    deg_in_i  = deg_out_i + NN;
    int*    counter   = deg_out_i + 2 * NN;
    int*    row_start = (int*)alloc(NN * sizeof(int));
    int*    cursor    = (int*)alloc(NN * sizeof(int));
    ushort* sorted    = (ushort*)alloc((NE + 3 * NN + 16) * sizeof(ushort));
    float*  norm_out  = (float*)alloc((NN + 1) * sizeof(float));   // [NN] = 0 (pad)
    float*  norm_in   = (float*)alloc(NN * sizeof(float));
    ushort* Wh0 = (ushort*)alloc(256 * 256 * sizeof(ushort));
    ushort* Wl0 = (ushort*)alloc(256 * 256 * sizeof(ushort));
    ushort* Wh1 = (ushort*)alloc(256 * 256 * sizeof(ushort));
    ushort* Wl1 = (ushort*)alloc(256 * 256 * sizeof(ushort));
    ushort* Wh2 = (ushort*)alloc(256 * 256 * sizeof(ushort));
    ushort* Wl2 = (ushort*)alloc(256 * 256 * sizeof(ushort));
    ushort* Ahb = (ushort*)alloc((size_t)MPAD * 256 * sizeof(ushort));  // split A hi (K-tiled)
    ushort* Alb = (ushort*)alloc((size_t)MPAD * 256 * sizeof(ushort));  // split A lo (K-tiled)
    float*  bufH = (float*)alloc(((size_t)NN * SS * 256 + 512) * sizeof(float)); // +zero pad row

    hipMemsetAsync(deg_out_i, 0, (2 * NN + 1) * sizeof(int), stream);
    hipMemsetAsync(bufH + (size_t)NN * 512, 0, 512 * sizeof(float), stream);  // pad row (src=NN)

    degree_kernel<<<(NE + 255) / 256, 256, 0, stream>>>(src, dst, deg_out_i, deg_in_i);
    alloc_kernel<<<(NN + 255) / 256, 256, 0, stream>>>(deg_out_i, deg_in_i, norm_out, norm_in,
                                                       row_start, cursor, counter);
    pad_fill<<<(NN + 255) / 256, 256, 0, stream>>>(row_start, deg_in_i, sorted);
    scatter_kernel<<<(NE + 255) / 256, 256, 0, stream>>>(src, dst, cursor, sorted);

    convert_w_all<<<dim3(256, 3), 256, 0, stream>>>(W0, W1, W2, Wh0, Wl0, Wh1, Wl1, Wh2, Wl2);
    init_out<<<(NN + 255) / 256, 256, 0, stream>>>(out, fcb, norm_out);
    zero_pads<<<16, 256, 0, stream>>>(Ahb, Alb);

    const int NB8 = (NN + 7) / 8;             // 2500 node groups (8 nodes/block)
    dim3 ggrid(MPAD / 64, 2);                 // 626 x 2 = 1252 blocks

    // Layer 0: feat [N][2*128] -> agg (norm gathers, row clamp) -> gemm(*norm_out) -> bufH
    aggregate4<64, 4, true><<<NB8 * 4, 128, 0, stream>>>(feat, row_start, deg_in_i, sorted,
                                                         norm_out, norm_in, Ahb, Alb);
    gemm_pipe<FIN, false><<<ggrid, 256, 0, stream>>>(Ahb, Alb, Wh0, Wl0, b0, bufH, fcw, norm_out);

    // Layer 1: bufH (pre-scaled by norm_out) -> pure-sum agg -> gemm(*norm_out) -> bufH
    aggregate4<128, 8, false><<<NB8 * 8, 128, 0, stream>>>(bufH, row_start, deg_in_i, sorted,
                                                           norm_out, norm_in, Ahb, Alb);
    gemm_pipe<256, false><<<ggrid, 256, 0, stream>>>(Ahb, Alb, Wh1, Wl1, b1, bufH, fcw, norm_out);

    // Layer 2: bufH -> pure-sum agg -> fused gemm -> out (atomicAdd; out pre-set to fcb)
    aggregate4<128, 8, false><<<NB8 * 8, 128, 0, stream>>>(bufH, row_start, deg_in_i, sorted,
                                                           norm_out, norm_in, Ahb, Alb);
    gemm_pipe<256, true><<<ggrid, 256, 0, stream>>>(Ahb, Alb, Wh2, Wl2, b2, out, fcw, norm_out);
}